// Round 11
// baseline (606.167 us; speedup 1.0000x reference)
//
#include <hip/hip_runtime.h>
#include <math.h>

#define NC   50000
#define NG   2000
#define DD   64
#define NE   1000000
#define NPOS 500000
#define WTH  (1.0f/3.0f)

#define GSTRIDE 640    // gene row capacity (mean deg 500, max ~590 observed)
#define CSTRIDE 64     // cell row capacity (mean deg 20, max ~45)

typedef unsigned short u16;
typedef unsigned char  u8;

__device__ __forceinline__ float bf2f(u16 u) {
    return __uint_as_float(((unsigned)u) << 16);
}
__device__ __forceinline__ u16 f2bf(float f) {   // round-to-nearest-even
    unsigned x = __float_as_uint(f);
    return (u16)((x + 0x7FFFu + ((x >> 16) & 1u)) >> 16);
}
__device__ __forceinline__ float blo(unsigned u) { return __uint_as_float(u << 16); }
__device__ __forceinline__ float bhi(unsigned u) { return __uint_as_float(u & 0xFFFF0000u); }
__device__ __forceinline__ float rdlane(float v, int l) {
    return __uint_as_float((unsigned)__builtin_amdgcn_readlane(__float_as_uint(v), l));
}

// ---------------- DIRECT adjacency build: one thread per edge, global atomics ----------------
// Replaces the 3-kernel radix pipeline (k_bin2 + k_binfill + k_binfill_g): max degrees
// (cell ~45 < 64, gene ~590 < 640) mean bucket overflow never binds, so per-node atomic
// cursors + direct scatter suffice. Saves ~37 MB bucket round-trip + ~12M LDS atomics.
// cnt_* end up as TRUE degrees (matches reference segment_sum exactly; consumers clamp).
// Entries are PRE-SCALED byte offsets: adj_c holds gene*256 (gfb row stride),
// adj_g holds cell*128 (cell-table row stride) -> no extract/mul in the hot gathers.
// NOTE: row order is atomic-nondeterministic -> fp32 gather-sum reassociation only
// (rounds 8-9 verified reassociation passes at identical absmax scale).
__global__ __launch_bounds__(256) void k_build(
    const int* __restrict__ s1, const int* __restrict__ d1,
    const int* __restrict__ s2, const int* __restrict__ d2,
    int* __restrict__ cnt_c1, int* __restrict__ cnt_c2,
    int* __restrict__ cnt_g1, int* __restrict__ cnt_g2,
    unsigned* __restrict__ adj_c1, unsigned* __restrict__ adj_c2,
    unsigned* __restrict__ adj_g1, unsigned* __restrict__ adj_g2)
{
    const int* src; const int* dst; int* cc; int* cg; unsigned* ac; unsigned* ag;
    if (blockIdx.y == 0) { src = s1; dst = d1; cc = cnt_c1; cg = cnt_g1; ac = adj_c1; ag = adj_g1; }
    else                 { src = s2; dst = d2; cc = cnt_c2; cg = cnt_g2; ac = adj_c2; ag = adj_g2; }
    int e = blockIdx.x * 256 + threadIdx.x;
    if (e >= NE) return;
    int s = src[e], g = dst[e];
    int p = atomicAdd(&cc[s], 1);
    if (p < CSTRIDE) ac[(size_t)s * CSTRIDE + p] = ((unsigned)g) << 8;   // gene*256
    int q = atomicAdd(&cg[g], 1);
    if (q < GSTRIDE) ag[(size_t)g * GSTRIDE + q] = ((unsigned)s) << 7;   // cell*128
}

// ---------------- norms + pre-scaled bf16 table conversion, wave per row ----------------
// Gene tables gfb1/gfb2 are LAYER-INTERLEAVED [NG][2*DD] u16: even slot = layer-1
// (gf*ci), odd slot = layer-2 (gn*ci, written later by k_c2g). One dword gather in
// k_g2c2_emb then serves BOTH layers (same index, halved VMEM issue).
__global__ __launch_bounds__(256) void k_prep(
    const int* __restrict__ cnt_c1, const int* __restrict__ cnt_c2,
    const int* __restrict__ cnt_g1, const int* __restrict__ cnt_g2,
    const float* __restrict__ cell1, const float* __restrict__ cell2,
    const float* __restrict__ gfeat,
    float* __restrict__ cj_c1, float* __restrict__ cj_c2,
    float* __restrict__ ci_g1, float* __restrict__ ci_g2,
    u16* __restrict__ t1s, u16* __restrict__ t2s,
    u16* __restrict__ gfb1, u16* __restrict__ gfb2)
{
    int i = blockIdx.x * 4 + (threadIdx.x >> 6);
    int d = threadIdx.x & 63;
    if (i < NC) {
        int a = cnt_c1[i]; float j1 = (a > 0) ? 1.0f / sqrtf((float)a) : 0.0f;
        int b = cnt_c2[i]; float j2 = (b > 0) ? 1.0f / sqrtf((float)b) : 0.0f;
        if (d == 0) { cj_c1[i] = j1; cj_c2[i] = j2; }
        int idx = i * DD + d;
        t1s[idx] = f2bf(cell1[idx] * j1);
        t2s[idx] = f2bf(cell2[idx] * j2);
    }
    if (i < NG) {
        int a = cnt_g1[i]; float j1 = (a > 0) ? 1.0f / sqrtf((float)a) : 0.0f;
        int b = cnt_g2[i]; float j2 = (b > 0) ? 1.0f / sqrtf((float)b) : 0.0f;
        if (d == 0) { ci_g1[i] = j1; ci_g2[i] = j2; }
        int idx = i * DD + d;
        float g = gfeat[idx];
        gfb1[2 * idx] = f2bf(g * j1);   // layer-1, even slot
        gfb2[2 * idx] = f2bf(g * j2);
    }
}

// ---------------- cell->gene SPMM, block per gene; adj_g holds byte offsets ----------------
__global__ __launch_bounds__(256) void k_c2g(
    const u16* __restrict__ src1s, const u16* __restrict__ src2s,
    const unsigned* __restrict__ adj_g1, const int* __restrict__ cnt_g1,
    const unsigned* __restrict__ adj_g2, const int* __restrict__ cnt_g2,
    const float* __restrict__ ci_g1, const float* __restrict__ ci_g2,
    u16* __restrict__ gb1s, u16* __restrict__ gb2s,   // nullable: interleaved tables; write ODD slot [2*idx+1]
    const float* __restrict__ gfeat_init,             // non-null: ih = w*(gfeat+gn); else ihb = bf16(ih + w*gn)
    float* __restrict__ ih, u16* __restrict__ ihb)
{
    __shared__ float l1[4][DD];
    __shared__ float l2[4][DD];
    int i   = blockIdx.x;
    int d   = threadIdx.x & 63;
    int grp = threadIdx.x >> 6;
    int d2b = 2 * d;                      // byte offset of dim d within a 128B row
    const char* sb1 = (const char*)src1s;
    const char* sb2 = (const char*)src2s;

    int n1 = cnt_g1[i]; if (n1 > GSTRIDE) n1 = GSTRIDE;
    const unsigned* a1 = adj_g1 + (size_t)i * GSTRIDE;
    float acc1 = 0.f;
    int e = 0;
    for (; e + 32 <= n1; e += 32) {   // group grp owns contiguous 8; two 16B offset loads
        uint4 wa = *(const uint4*)(a1 + e + grp * 8);
        uint4 wb = *(const uint4*)(a1 + e + grp * 8 + 4);
        float v0 = bf2f(*(const u16*)(sb1 + wa.x + d2b)), v1 = bf2f(*(const u16*)(sb1 + wa.y + d2b));
        float v2 = bf2f(*(const u16*)(sb1 + wa.z + d2b)), v3 = bf2f(*(const u16*)(sb1 + wa.w + d2b));
        float v4 = bf2f(*(const u16*)(sb1 + wb.x + d2b)), v5 = bf2f(*(const u16*)(sb1 + wb.y + d2b));
        float v6 = bf2f(*(const u16*)(sb1 + wb.z + d2b)), v7 = bf2f(*(const u16*)(sb1 + wb.w + d2b));
        acc1 += ((v0 + v1) + (v2 + v3)) + ((v4 + v5) + (v6 + v7));
    }
    for (int q = e + grp; q < n1; q += 4) acc1 += bf2f(*(const u16*)(sb1 + a1[q] + d2b));

    int n2 = cnt_g2[i]; if (n2 > GSTRIDE) n2 = GSTRIDE;
    const unsigned* a2 = adj_g2 + (size_t)i * GSTRIDE;
    float acc2 = 0.f;
    e = 0;
    for (; e + 32 <= n2; e += 32) {
        uint4 wa = *(const uint4*)(a2 + e + grp * 8);
        uint4 wb = *(const uint4*)(a2 + e + grp * 8 + 4);
        float v0 = bf2f(*(const u16*)(sb2 + wa.x + d2b)), v1 = bf2f(*(const u16*)(sb2 + wa.y + d2b));
        float v2 = bf2f(*(const u16*)(sb2 + wa.z + d2b)), v3 = bf2f(*(const u16*)(sb2 + wa.w + d2b));
        float v4 = bf2f(*(const u16*)(sb2 + wb.x + d2b)), v5 = bf2f(*(const u16*)(sb2 + wb.y + d2b));
        float v6 = bf2f(*(const u16*)(sb2 + wb.z + d2b)), v7 = bf2f(*(const u16*)(sb2 + wb.w + d2b));
        acc2 += ((v0 + v1) + (v2 + v3)) + ((v4 + v5) + (v6 + v7));
    }
    for (int q = e + grp; q < n2; q += 4) acc2 += bf2f(*(const u16*)(sb2 + a2[q] + d2b));

    l1[grp][d] = acc1; l2[grp][d] = acc2;
    __syncthreads();
    if (grp == 0) {
        float s1 = l1[0][d] + l1[1][d] + l1[2][d] + l1[3][d];
        float s2 = l2[0][d] + l2[1][d] + l2[2][d] + l2[3][d];
        float ci1 = ci_g1[i], ci2 = ci_g2[i];
        float gn = 0.5f * (ci1 * s1 + ci2 * s2);
        int idx = i * DD + d;
        if (gb1s) { gb1s[2 * idx + 1] = f2bf(gn * ci1); gb2s[2 * idx + 1] = f2bf(gn * ci2); }
        if (gfeat_init) ih[idx] = WTH * (gfeat_init[idx] + gn);
        else            ihb[idx] = f2bf(ih[idx] + WTH * gn);
    }
}

// ---------------- FUSED gene->cell (layer1 + layer2) + emb + BN + ELU ----------------
// Wave per cell (grid-stride); lane d = dim d. ONE pass over adj_c serves both layers:
// per edge, ONE dword gather from the layer-interleaved table per relation
// (lo bf16 = layer-1, hi bf16 = layer-2). adj_c holds PRE-SCALED byte offsets
// (gene*256) -> per gather: one v_add, no extract/mul.
// Matvec: round-6 readlane construct (split-acc was neutral, round 9).
// DO NOT: (a) float4-LDS matvec (rounds 1-3: ~110 MB scratch spill); (b) launch_bounds
// min-waves > 4 (round 2: VGPR 32 -> 582 MB spill); (c) Wt/float4 weight preload
// (round 7: allocator remats regardless, -9 us). Spill tripwire: WRITE_SIZE > 30 MB.
__global__ __launch_bounds__(256, 4) void k_g2c2_emb(
    const u16* __restrict__ gfb1, const u16* __restrict__ gfb2,  // interleaved [NG][2*DD]
    const unsigned* __restrict__ adj_c1, const int* __restrict__ cnt_c1,
    const unsigned* __restrict__ adj_c2, const int* __restrict__ cnt_c2,
    const float* __restrict__ cj_c1, const float* __restrict__ cj_c2,
    const float* __restrict__ cell1, const float* __restrict__ cell2,
    u16* __restrict__ c1bs, u16* __restrict__ c2bs,
    u16* __restrict__ uf1b, u16* __restrict__ uf2b,
    const float* __restrict__ W, const float* __restrict__ bb,
    const float* __restrict__ gam, const float* __restrict__ bet,
    const float* __restrict__ mea, const float* __restrict__ var)
{
    int d = threadIdx.x & 63;
    int wid = blockIdx.x * 4 + (threadIdx.x >> 6);
    int nw = gridDim.x * 4;

    float Wl[DD];
    #pragma unroll
    for (int k = 0; k < DD; k++) Wl[k] = W[k * DD + d];
    float inv = 1.0f / sqrtf(var[d] + 1e-5f);
    float ga = gam[d], be = bet[d], me = mea[d];
    float bias1 = bb[d] + W[DD * DD + d];
    float bias2 = bb[d] + W[(DD + 1) * DD + d];
    int d4 = 4 * d;                       // byte offset of lane's dword within 256B row
    const char* gb1 = (const char*)gfb1;
    const char* gb2 = (const char*)gfb2;

    for (int i = wid; i < NC; i += nw) {
        int n1 = cnt_c1[i]; if (n1 > CSTRIDE) n1 = CSTRIDE;
        int n2 = cnt_c2[i]; if (n2 > CSTRIDE) n2 = CSTRIDE;
        const unsigned* a1 = adj_c1 + (size_t)i * CSTRIDE;
        const unsigned* a2 = adj_c2 + (size_t)i * CSTRIDE;
        float a1A = 0.f, a2A = 0.f;   // layer-1 sums (rel 1, rel 2)
        float a1B = 0.f, a2B = 0.f;   // layer-2 sums
        int e1 = 0, e2 = 0;
        int m1 = n1 & ~3, m2 = n2 & ~3;
        int m = (m1 < m2) ? m1 : m2;
        for (; e1 < m; e1 += 4, e2 += 4) {
            uint4 w1 = *(const uint4*)(a1 + e1);
            uint4 w2 = *(const uint4*)(a2 + e2);
            unsigned p0 = *(const unsigned*)(gb1 + w1.x + d4);
            unsigned p1 = *(const unsigned*)(gb1 + w1.y + d4);
            unsigned p2 = *(const unsigned*)(gb1 + w1.z + d4);
            unsigned p3 = *(const unsigned*)(gb1 + w1.w + d4);
            unsigned q0 = *(const unsigned*)(gb2 + w2.x + d4);
            unsigned q1 = *(const unsigned*)(gb2 + w2.y + d4);
            unsigned q2 = *(const unsigned*)(gb2 + w2.z + d4);
            unsigned q3 = *(const unsigned*)(gb2 + w2.w + d4);
            a1A += (blo(p0) + blo(p1)) + (blo(p2) + blo(p3));
            a1B += (bhi(p0) + bhi(p1)) + (bhi(p2) + bhi(p3));
            a2A += (blo(q0) + blo(q1)) + (blo(q2) + blo(q3));
            a2B += (bhi(q0) + bhi(q1)) + (bhi(q2) + bhi(q3));
        }
        for (; e1 + 3 < n1; e1 += 4) {
            uint4 w1 = *(const uint4*)(a1 + e1);
            unsigned p0 = *(const unsigned*)(gb1 + w1.x + d4);
            unsigned p1 = *(const unsigned*)(gb1 + w1.y + d4);
            unsigned p2 = *(const unsigned*)(gb1 + w1.z + d4);
            unsigned p3 = *(const unsigned*)(gb1 + w1.w + d4);
            a1A += (blo(p0) + blo(p1)) + (blo(p2) + blo(p3));
            a1B += (bhi(p0) + bhi(p1)) + (bhi(p2) + bhi(p3));
        }
        for (; e1 < n1; e1++) {
            unsigned p = *(const unsigned*)(gb1 + a1[e1] + d4);
            a1A += blo(p); a1B += bhi(p);
        }
        for (; e2 + 3 < n2; e2 += 4) {
            uint4 w2 = *(const uint4*)(a2 + e2);
            unsigned q0 = *(const unsigned*)(gb2 + w2.x + d4);
            unsigned q1 = *(const unsigned*)(gb2 + w2.y + d4);
            unsigned q2 = *(const unsigned*)(gb2 + w2.z + d4);
            unsigned q3 = *(const unsigned*)(gb2 + w2.w + d4);
            a2A += (blo(q0) + blo(q1)) + (blo(q2) + blo(q3));
            a2B += (bhi(q0) + bhi(q1)) + (bhi(q2) + bhi(q3));
        }
        for (; e2 < n2; e2++) {
            unsigned q = *(const unsigned*)(gb2 + a2[e2] + d4);
            a2A += blo(q); a2B += bhi(q);
        }

        float jc1 = cj_c1[i], jc2 = cj_c2[i];
        float c1n = jc1 * a1A;     // layer-1 cell output
        float c2n = jc2 * a2A;
        int idx = i * DD + d;
        c1bs[idx] = f2bf(c1n * jc1);
        c2bs[idx] = f2bf(c2n * jc2);
        // u1 = WTH*(cell+c1n); x = u1 + WTH*(cj*accB)  -- same order as unfused pair
        float x1 = WTH * (cell1[idx] + c1n) + WTH * (jc1 * a1B);
        float x2 = WTH * (cell2[idx] + c2n) + WTH * (jc2 * a2B);

        // emb matvec both relations (round-6 readlane construct, verbatim)
        float y1 = bias1, y2 = bias2;
        #pragma unroll
        for (int k = 0; k < DD; k++) {
            float xa = rdlane(x1, k);
            float xb = rdlane(x2, k);
            y1 += xa * Wl[k];
            y2 += xb * Wl[k];
        }
        float t1 = ga * (y1 - me) * inv + be;
        t1 = (t1 > 0.f) ? t1 : expm1f(t1);
        float t2 = ga * (y2 - me) * inv + be;
        t2 = (t2 > 0.f) ? t2 : expm1f(t2);
        uf1b[idx] = f2bf(t1);
        uf2b[idx] = f2bf(t2);
    }
}

// ---------------- decoder: bf16 dot, 8 lanes x 16B per edge ----------------
__global__ __launch_bounds__(256) void k_dec(
    const u16* __restrict__ uf1b, const u16* __restrict__ uf2b,
    const u16* __restrict__ ihb,
    const int* __restrict__ ps1, const int* __restrict__ pd1,
    const int* __restrict__ ps2, const int* __restrict__ pd2,
    float* __restrict__ out)
{
    int t = blockIdx.x * 256 + threadIdx.x;
    int e = t >> 3;
    int l = t & 7;
    if (e >= 2 * NPOS) return;
    const u16* uf; int s, g;
    if (e < NPOS) { uf = uf1b; s = ps1[e];        g = pd1[e];        }
    else          { uf = uf2b; s = ps2[e - NPOS]; g = pd2[e - NPOS]; }
    uint4 av = ((const uint4*)(uf + (size_t)s * DD))[l];
    uint4 cv = ((const uint4*)(ihb + (size_t)g * DD))[l];
    float acc = blo(av.x) * blo(cv.x) + bhi(av.x) * bhi(cv.x)
              + blo(av.y) * blo(cv.y) + bhi(av.y) * bhi(cv.y)
              + blo(av.z) * blo(cv.z) + bhi(av.z) * bhi(cv.z)
              + blo(av.w) * blo(cv.w) + bhi(av.w) * bhi(cv.w);
    acc += __shfl_xor(acc, 4);
    acc += __shfl_xor(acc, 2);
    acc += __shfl_xor(acc, 1);
    if (l == 0) out[e] = acc;
}

extern "C" void kernel_launch(void* const* d_in, const int* in_sizes, int n_in,
                              void* d_out, int out_size, void* d_ws, size_t ws_size,
                              hipStream_t stream)
{
    const float* cell1 = (const float*)d_in[0];
    const float* cell2 = (const float*)d_in[1];
    const float* gfeat = (const float*)d_in[2];
    const float* embW  = (const float*)d_in[3];
    const float* embB  = (const float*)d_in[4];
    const float* bng   = (const float*)d_in[5];
    const float* bnb   = (const float*)d_in[6];
    const float* bnm   = (const float*)d_in[7];
    const float* bnv   = (const float*)d_in[8];
    const int* es1 = (const int*)d_in[9];
    const int* ed1 = (const int*)d_in[10];
    const int* es2 = (const int*)d_in[11];
    const int* ed2 = (const int*)d_in[12];
    const int* ps1 = (const int*)d_in[13];
    const int* pd1 = (const int*)d_in[14];
    const int* ps2 = (const int*)d_in[15];
    const int* pd2 = (const int*)d_in[16];
    float* out = (float*)d_out;

    char* base = (char*)d_ws;
    size_t off = 0;
    auto alloc = [&](size_t bytes) -> void* {
        void* p = base + off;
        off = (off + bytes + 255) & ~(size_t)255;
        return p;
    };
    // zeroed counters first: one memset covers all four cnt arrays (atomic cursors)
    int* cnt_c1 = (int*)alloc((size_t)NC * 4);
    int* cnt_c2 = (int*)alloc((size_t)NC * 4);
    int* cnt_g1 = (int*)alloc((size_t)NG * 4);
    int* cnt_g2 = (int*)alloc((size_t)NG * 4);
    size_t cntEnd = off;                       // zero [0, cntEnd) ~417 KB
    unsigned* adj_c1 = (unsigned*)alloc((size_t)NC * CSTRIDE * 4); // 12.8 MB (u32 byte offsets)
    unsigned* adj_c2 = (unsigned*)alloc((size_t)NC * CSTRIDE * 4);
    unsigned* adj_g1 = (unsigned*)alloc((size_t)NG * GSTRIDE * 4); // 5.1 MB (u32 byte offsets)
    unsigned* adj_g2 = (unsigned*)alloc((size_t)NG * GSTRIDE * 4);
    float* cj_c1 = (float*)alloc((size_t)NC * 4);
    float* cj_c2 = (float*)alloc((size_t)NC * 4);
    float* ci_g1 = (float*)alloc((size_t)NG * 4);
    float* ci_g2 = (float*)alloc((size_t)NG * 4);
    u16* t1s  = (u16*)alloc((size_t)NC * DD * 2);   // bf16(cell1*cj_c1); reused as uf1b
    u16* t2s  = (u16*)alloc((size_t)NC * DD * 2);   // bf16(cell2*cj_c2); reused as uf2b
    u16* c1bs = (u16*)alloc((size_t)NC * DD * 2);
    u16* c2bs = (u16*)alloc((size_t)NC * DD * 2);
    u16* gfb1 = (u16*)alloc((size_t)NG * DD * 2 * 2);  // interleaved L1|L2 gene table, rel 1 (512 KB)
    u16* gfb2 = (u16*)alloc((size_t)NG * DD * 2 * 2);  // interleaved L1|L2 gene table, rel 2
    float* ih  = (float*)alloc((size_t)NG * DD * 4);
    u16*   ihb = (u16*)alloc((size_t)NG * DD * 2);
    (void)ws_size; (void)in_sizes; (void)n_in; (void)out_size;

    hipMemsetAsync(d_ws, 0, cntEnd, stream);

    // ---- direct adjacency build (replaces radix bin + 2 binfills) ----
    dim3 gb((NE + 255) / 256, 2);
    k_build<<<gb, 256, 0, stream>>>(es1, ed1, es2, ed2,
                                    cnt_c1, cnt_c2, cnt_g1, cnt_g2,
                                    adj_c1, adj_c2, adj_g1, adj_g2);
    k_prep<<<(NC + 3) / 4, 256, 0, stream>>>(cnt_c1, cnt_c2, cnt_g1, cnt_g2,
                                             cell1, cell2, gfeat,
                                             cj_c1, cj_c2, ci_g1, ci_g2,
                                             t1s, t2s, gfb1, gfb2);

    // ---- layer 1 cell->gene: fills ODD slots of gfb (gn*ci) + ih ----
    k_c2g<<<NG, 256, 0, stream>>>(t1s, t2s, adj_g1, cnt_g1, adj_g2, cnt_g2,
                                  ci_g1, ci_g2, gfb1, gfb2, gfeat, ih, nullptr);
    // ---- FUSED gene->cell layer1+layer2 + emb + BN + ELU (t1s/t2s reused as uf) ----
    k_g2c2_emb<<<2048, 256, 0, stream>>>(gfb1, gfb2,
                                         adj_c1, cnt_c1, adj_c2, cnt_c2,
                                         cj_c1, cj_c2, cell1, cell2,
                                         c1bs, c2bs, t1s, t2s,
                                         embW, embB, bng, bnb, bnm, bnv);
    // ---- layer 2 cell->gene -> ihb ----
    k_c2g<<<NG, 256, 0, stream>>>(c1bs, c2bs, adj_g1, cnt_g1, adj_g2, cnt_g2,
                                  ci_g1, ci_g2, nullptr, nullptr, nullptr, ih, ihb);
    // ---- decoder ----
    k_dec<<<(2 * NPOS * 8 + 255) / 256, 256, 0, stream>>>(t1s, t2s, ihb,
                                                          ps1, pd1, ps2, pd2, out);
}

// Round 12
// 355.260 us; speedup vs baseline: 1.7063x; 1.7063x over previous
//
#include <hip/hip_runtime.h>
#include <math.h>

#define NC   50000
#define NG   2000
#define DD   64
#define NE   1000000
#define NPOS 500000
#define WTH  (1.0f/3.0f)

#define GSTRIDE 640    // gene bucket capacity (mean deg 500, max ~590 observed)
#define CSTRIDE 64     // cell bucket capacity (mean deg 20, max ~45)

#define NRNGB  256     // cell ranges for radix bin
#define RNGCB  196     // cells per range (256*196 = 50176 >= NC)
#define RCAP   4608    // cell-bucket capacity per (range, relation): 3920 +11 sigma
#define NRNGG  250     // gene ranges
#define GPRG   8       // genes per range (250*8 = 2000)
#define RCAPG  4608    // gene-bucket capacity per (range, relation): 4000 +9 sigma
#define CHUNKB 4096    // edges per bin2 block -> 245x2 = 490 blocks

typedef unsigned short u16;
typedef unsigned char  u8;

__device__ __forceinline__ float bf2f(u16 u) {
    return __uint_as_float(((unsigned)u) << 16);
}
__device__ __forceinline__ u16 f2bf(float f) {   // round-to-nearest-even
    unsigned x = __float_as_uint(f);
    return (u16)((x + 0x7FFFu + ((x >> 16) & 1u)) >> 16);
}
__device__ __forceinline__ float blo(unsigned u) { return __uint_as_float(u << 16); }
__device__ __forceinline__ float bhi(unsigned u) { return __uint_as_float(u & 0xFFFF0000u); }
__device__ __forceinline__ float rdlane(float v, int l) {
    return __uint_as_float((unsigned)__builtin_amdgcn_readlane(__float_as_uint(v), l));
}

// ---------------- unified radix bin: edges -> cell buckets AND gene buckets ----------------
// DO NOT replace with direct atomic scatter (round 11: 4M scattered stores -> 215 MB
// write amplification, 300 us). The LDS staging here is what coalesces the writes.
__global__ __launch_bounds__(256) void k_bin2(
    const int* __restrict__ s1, const int* __restrict__ d1,
    const int* __restrict__ s2, const int* __restrict__ d2,
    int* __restrict__ rcnt_c1, int* __restrict__ rcnt_c2,
    int* __restrict__ rcnt_g1, int* __restrict__ rcnt_g2,
    unsigned* __restrict__ rbc1, unsigned* __restrict__ rbc2,
    unsigned* __restrict__ rbg1, unsigned* __restrict__ rbg2)
{
    __shared__ unsigned ed[CHUNKB];            // 16 KB staged edges (src<<16|gene)
    __shared__ unsigned hc[NRNGB], bc[NRNGB];
    __shared__ unsigned hg[NRNGG], bg[NRNGG];
    const int* src; const int* dst; int* rc; int* rg; unsigned* rbc; unsigned* rbg;
    if (blockIdx.y == 0) { src = s1; dst = d1; rc = rcnt_c1; rg = rcnt_g1; rbc = rbc1; rbg = rbg1; }
    else                 { src = s2; dst = d2; rc = rcnt_c2; rg = rcnt_g2; rbc = rbc2; rbg = rbg2; }
    int t = threadIdx.x;
    if (t < NRNGB) hc[t] = 0;
    if (t < NRNGG) hg[t] = 0;
    __syncthreads();
    int e0 = blockIdx.x * CHUNKB;
    #pragma unroll 4
    for (int i = 0; i < CHUNKB / 256; i++) {
        int e = e0 + i * 256 + t;
        unsigned pk = 0xFFFFFFFFu;
        if (e < NE) {
            int s = src[e], g = dst[e];
            pk = ((unsigned)s << 16) | (unsigned)g;
            atomicAdd(&hc[s / RNGCB], 1u);
            atomicAdd(&hg[g >> 3], 1u);
        }
        ed[i * 256 + t] = pk;
    }
    __syncthreads();
    if (t < NRNGB) { unsigned c = hc[t]; bc[t] = c ? (unsigned)atomicAdd(&rc[t], (int)c) : 0u; hc[t] = 0; }
    if (t < NRNGG) { unsigned c = hg[t]; bg[t] = c ? (unsigned)atomicAdd(&rg[t], (int)c) : 0u; hg[t] = 0; }
    __syncthreads();
    #pragma unroll 4
    for (int i = 0; i < CHUNKB / 256; i++) {
        unsigned pk = ed[i * 256 + t];
        if (pk != 0xFFFFFFFFu) {
            int s = (int)(pk >> 16), g = (int)(pk & 0xFFFFu);
            int r1 = s / RNGCB;
            unsigned p = bc[r1] + atomicAdd(&hc[r1], 1u);
            if (p < RCAP)
                rbc[(size_t)r1 * RCAP + p] = ((unsigned)(s - r1 * RNGCB) << 16) | (unsigned)g;
            int r2 = g >> 3;
            unsigned q = bg[r2] + atomicAdd(&hg[r2], 1u);
            if (q < RCAPG)
                rbg[(size_t)r2 * RCAPG + q] = ((unsigned)(g & 7) << 16) | (unsigned)s;
        }
    }
}

// ---------------- cell buckets -> dense adj_c rows + cnt_c + FUSED cell prep ----------------
// After scattering its range's rows, each block also computes (for its relation) the
// degree norms cj and the pre-scaled bf16 table ts = bf16(cellF * cj) -- formerly
// k_prep's cell half. Same clamped counts, same expressions -> bit-identical values.
__global__ __launch_bounds__(256) void k_binfill(
    const int* __restrict__ rcnt1, const int* __restrict__ rcnt2,
    const unsigned* __restrict__ rbuf1, const unsigned* __restrict__ rbuf2,
    u16* __restrict__ adj_c1, u16* __restrict__ adj_c2,
    int* __restrict__ cnt_c1, int* __restrict__ cnt_c2,
    const float* __restrict__ cell1, const float* __restrict__ cell2,
    float* __restrict__ cj_c1, float* __restrict__ cj_c2,
    u16* __restrict__ t1s, u16* __restrict__ t2s)
{
    __shared__ u16 rows[RNGCB * CSTRIDE];       // 24.5 KB
    __shared__ unsigned cur[(RNGCB + 3) / 4];   // packed u8 cursors
    const int* rcnt; const unsigned* rbuf; u16* adj; int* cnt;
    const float* cellF; float* cj; u16* ts;
    if (blockIdx.y == 0) { rcnt = rcnt1; rbuf = rbuf1; adj = adj_c1; cnt = cnt_c1;
                           cellF = cell1; cj = cj_c1; ts = t1s; }
    else                 { rcnt = rcnt2; rbuf = rbuf2; adj = adj_c2; cnt = cnt_c2;
                           cellF = cell2; cj = cj_c2; ts = t2s; }
    int t = threadIdx.x;
    int r = blockIdx.x;
    if (t < (RNGCB + 3) / 4) cur[t] = 0;
    __syncthreads();
    int n = rcnt[r]; if (n > RCAP) n = RCAP;
    const unsigned* buf = rbuf + (size_t)r * RCAP;
    for (int i = t; i < n; i += 256) {
        unsigned e = buf[i];
        unsigned cl = e >> 16;
        unsigned sh = 8u * (cl & 3u);
        unsigned old = atomicAdd(&cur[cl >> 2], 1u << sh);
        unsigned p = (old >> sh) & 0xFFu;
        if (p < CSTRIDE) rows[cl * CSTRIDE + p] = (u16)(e & 0xFFFFu);
    }
    __syncthreads();
    int lo = r * RNGCB;
    int valid = NC - lo; if (valid > RNGCB) valid = RNGCB;
    if (valid <= 0) return;
    if (t < valid) {
        unsigned p = (cur[t >> 2] >> (8u * (t & 3u))) & 0xFFu;
        cnt[lo + t] = (int)((p > CSTRIDE) ? CSTRIDE : p);
    }
    uint4* gd = (uint4*)(adj + (size_t)lo * CSTRIDE);
    const uint4* ls = (const uint4*)rows;
    for (int i = t; i < valid * (CSTRIDE / 8); i += 256) gd[i] = ls[i];
    // fused k_prep cell half for this range/relation
    for (int x = t; x < valid * DD; x += 256) {
        int cl = x >> 6, dd = x & 63;
        unsigned p = (cur[cl >> 2] >> (8u * (cl & 3u))) & 0xFFu;
        int nn = (p > CSTRIDE) ? CSTRIDE : (int)p;
        float j = (nn > 0) ? 1.0f / sqrtf((float)nn) : 0.0f;
        int idx = (lo + cl) * DD + dd;
        ts[idx] = f2bf(cellF[idx] * j);
        if (dd == 0) cj[lo + cl] = j;
    }
}

// ---------------- gene buckets -> dense adj_g rows + cnt_g + FUSED gene prep ----------------
// Also fills ci_g and the EVEN (layer-1) slots of the interleaved gfb table for its
// relation -- formerly k_prep's gene half. Bit-identical values.
__global__ __launch_bounds__(256) void k_binfill_g(
    const int* __restrict__ rcnt1, const int* __restrict__ rcnt2,
    const unsigned* __restrict__ rbuf1, const unsigned* __restrict__ rbuf2,
    u16* __restrict__ adj_g1, u16* __restrict__ adj_g2,
    int* __restrict__ cnt_g1, int* __restrict__ cnt_g2,
    const float* __restrict__ gfeat,
    float* __restrict__ ci_g1, float* __restrict__ ci_g2,
    u16* __restrict__ gfb1, u16* __restrict__ gfb2)
{
    __shared__ u16 rows[GPRG * GSTRIDE];   // 10 KB staged gene rows
    __shared__ unsigned cur[GPRG];
    const int* rcnt; const unsigned* rbuf; u16* adj; int* cnt; float* ci; u16* gfb;
    if (blockIdx.y == 0) { rcnt = rcnt1; rbuf = rbuf1; adj = adj_g1; cnt = cnt_g1;
                           ci = ci_g1; gfb = gfb1; }
    else                 { rcnt = rcnt2; rbuf = rbuf2; adj = adj_g2; cnt = cnt_g2;
                           ci = ci_g2; gfb = gfb2; }
    int t = threadIdx.x;
    int r = blockIdx.x;
    if (t < GPRG) cur[t] = 0;
    __syncthreads();
    int n = rcnt[r]; if (n > RCAPG) n = RCAPG;
    const unsigned* buf = rbuf + (size_t)r * RCAPG;
    for (int i = t; i < n; i += 256) {
        unsigned e = buf[i];
        unsigned gl = e >> 16;
        unsigned p = atomicAdd(&cur[gl], 1u);
        if (p < GSTRIDE) rows[gl * GSTRIDE + p] = (u16)(e & 0xFFFFu);
    }
    __syncthreads();
    if (t < GPRG) {
        unsigned p = cur[t];
        cnt[r * GPRG + t] = (int)((p > GSTRIDE) ? GSTRIDE : p);
    }
    uint4* gd = (uint4*)(adj + (size_t)r * GPRG * GSTRIDE);
    const uint4* ls = (const uint4*)rows;
    for (int i = t; i < GPRG * GSTRIDE / 8; i += 256) gd[i] = ls[i];
    // fused k_prep gene half for this range/relation (even slots of gfb)
    for (int x = t; x < GPRG * DD; x += 256) {
        int gl = x >> 6, dd = x & 63;
        unsigned p = cur[gl];
        int nn = (p > GSTRIDE) ? GSTRIDE : (int)p;
        float j = (nn > 0) ? 1.0f / sqrtf((float)nn) : 0.0f;
        int gene = r * GPRG + gl;
        int idx = gene * DD + dd;
        gfb[2 * idx] = f2bf(gfeat[idx] * j);
        if (dd == 0) ci[gene] = j;
    }
}

// ---------------- cell->gene SPMM, block per gene, contiguous uint4 index loads ----------------
__global__ __launch_bounds__(256) void k_c2g(
    const u16* __restrict__ src1s, const u16* __restrict__ src2s,
    const u16* __restrict__ adj_g1, const int* __restrict__ cnt_g1,
    const u16* __restrict__ adj_g2, const int* __restrict__ cnt_g2,
    const float* __restrict__ ci_g1, const float* __restrict__ ci_g2,
    u16* __restrict__ gb1s, u16* __restrict__ gb2s,   // nullable: interleaved tables; write ODD slot [2*idx+1]
    const float* __restrict__ gfeat_init,             // non-null: ih = w*(gfeat+gn); else ihb = bf16(ih + w*gn)
    float* __restrict__ ih, u16* __restrict__ ihb)
{
    __shared__ float l1[4][DD];
    __shared__ float l2[4][DD];
    int i   = blockIdx.x;
    int d   = threadIdx.x & 63;
    int grp = threadIdx.x >> 6;

    int n1 = cnt_g1[i]; if (n1 > GSTRIDE) n1 = GSTRIDE;
    const u16* a1 = adj_g1 + i * GSTRIDE;
    float acc1 = 0.f;
    int e = 0;
    for (; e + 32 <= n1; e += 32) {   // group grp owns contiguous 8; one 16B index load
        uint4 w = *(const uint4*)(a1 + e + grp * 8);
        int s0 = w.x & 0xFFFF, s1 = w.x >> 16, s2 = w.y & 0xFFFF, s3 = w.y >> 16;
        int s4 = w.z & 0xFFFF, s5 = w.z >> 16, s6 = w.w & 0xFFFF, s7 = w.w >> 16;
        float v0 = bf2f(src1s[s0 * DD + d]), v1 = bf2f(src1s[s1 * DD + d]);
        float v2 = bf2f(src1s[s2 * DD + d]), v3 = bf2f(src1s[s3 * DD + d]);
        float v4 = bf2f(src1s[s4 * DD + d]), v5 = bf2f(src1s[s5 * DD + d]);
        float v6 = bf2f(src1s[s6 * DD + d]), v7 = bf2f(src1s[s7 * DD + d]);
        acc1 += ((v0 + v1) + (v2 + v3)) + ((v4 + v5) + (v6 + v7));
    }
    for (int q = e + grp; q < n1; q += 4) acc1 += bf2f(src1s[a1[q] * DD + d]);

    int n2 = cnt_g2[i]; if (n2 > GSTRIDE) n2 = GSTRIDE;
    const u16* a2 = adj_g2 + i * GSTRIDE;
    float acc2 = 0.f;
    e = 0;
    for (; e + 32 <= n2; e += 32) {
        uint4 w = *(const uint4*)(a2 + e + grp * 8);
        int s0 = w.x & 0xFFFF, s1 = w.x >> 16, s2 = w.y & 0xFFFF, s3 = w.y >> 16;
        int s4 = w.z & 0xFFFF, s5 = w.z >> 16, s6 = w.w & 0xFFFF, s7 = w.w >> 16;
        float v0 = bf2f(src2s[s0 * DD + d]), v1 = bf2f(src2s[s1 * DD + d]);
        float v2 = bf2f(src2s[s2 * DD + d]), v3 = bf2f(src2s[s3 * DD + d]);
        float v4 = bf2f(src2s[s4 * DD + d]), v5 = bf2f(src2s[s5 * DD + d]);
        float v6 = bf2f(src2s[s6 * DD + d]), v7 = bf2f(src2s[s7 * DD + d]);
        acc2 += ((v0 + v1) + (v2 + v3)) + ((v4 + v5) + (v6 + v7));
    }
    for (int q = e + grp; q < n2; q += 4) acc2 += bf2f(src2s[a2[q] * DD + d]);

    l1[grp][d] = acc1; l2[grp][d] = acc2;
    __syncthreads();
    if (grp == 0) {
        float s1 = l1[0][d] + l1[1][d] + l1[2][d] + l1[3][d];
        float s2 = l2[0][d] + l2[1][d] + l2[2][d] + l2[3][d];
        float ci1 = ci_g1[i], ci2 = ci_g2[i];
        float gn = 0.5f * (ci1 * s1 + ci2 * s2);
        int idx = i * DD + d;
        if (gb1s) { gb1s[2 * idx + 1] = f2bf(gn * ci1); gb2s[2 * idx + 1] = f2bf(gn * ci2); }
        if (gfeat_init) ih[idx] = WTH * (gfeat_init[idx] + gn);
        else            ihb[idx] = f2bf(ih[idx] + WTH * gn);
    }
}

// ---------------- FUSED gene->cell (layer1 + layer2) + emb + BN + ELU ----------------
// Wave per cell (grid-stride); lane d = dim d. ONE pass over adj_c serves both layers:
// per edge, ONE dword gather from the layer-interleaved table per relation
// (lo bf16 = layer-1, hi bf16 = layer-2).
// Matvec: round-6 readlane construct (split-acc neutral r9; Wt preload remats r7).
// DO NOT: (a) float4-LDS matvec (rounds 1-3: ~110 MB scratch spill); (b) launch_bounds
// min-waves > 4 (round 2: VGPR 32 -> 582 MB spill); (c) u32 byte-offset adjacency
// (round 10: hot kernel -2.5us but preprocessing +10us). Spill tripwire: WRITE > 30 MB.
__global__ __launch_bounds__(256, 4) void k_g2c2_emb(
    const u16* __restrict__ gfb1, const u16* __restrict__ gfb2,  // interleaved [NG][2*DD]
    const u16* __restrict__ adj_c1, const int* __restrict__ cnt_c1,
    const u16* __restrict__ adj_c2, const int* __restrict__ cnt_c2,
    const float* __restrict__ cj_c1, const float* __restrict__ cj_c2,
    const float* __restrict__ cell1, const float* __restrict__ cell2,
    u16* __restrict__ c1bs, u16* __restrict__ c2bs,
    u16* __restrict__ uf1b, u16* __restrict__ uf2b,
    const float* __restrict__ W, const float* __restrict__ bb,
    const float* __restrict__ gam, const float* __restrict__ bet,
    const float* __restrict__ mea, const float* __restrict__ var)
{
    int d = threadIdx.x & 63;
    int wid = blockIdx.x * 4 + (threadIdx.x >> 6);
    int nw = gridDim.x * 4;

    float Wl[DD];
    #pragma unroll
    for (int k = 0; k < DD; k++) Wl[k] = W[k * DD + d];
    float inv = 1.0f / sqrtf(var[d] + 1e-5f);
    float ga = gam[d], be = bet[d], me = mea[d];
    float bias1 = bb[d] + W[DD * DD + d];
    float bias2 = bb[d] + W[(DD + 1) * DD + d];
    int d2 = 2 * d;

    for (int i = wid; i < NC; i += nw) {
        int n1 = cnt_c1[i]; if (n1 > CSTRIDE) n1 = CSTRIDE;
        int n2 = cnt_c2[i]; if (n2 > CSTRIDE) n2 = CSTRIDE;
        const u16* a1 = adj_c1 + (size_t)i * CSTRIDE;
        const u16* a2 = adj_c2 + (size_t)i * CSTRIDE;
        float a1A = 0.f, a2A = 0.f;   // layer-1 sums (rel 1, rel 2)
        float a1B = 0.f, a2B = 0.f;   // layer-2 sums
        int e1 = 0, e2 = 0;
        int m1 = n1 & ~3, m2 = n2 & ~3;
        int m = (m1 < m2) ? m1 : m2;
        for (; e1 < m; e1 += 4, e2 += 4) {
            uint2 w1 = *(const uint2*)(a1 + e1);
            uint2 w2 = *(const uint2*)(a2 + e2);
            int j0 = w1.x & 0xFFFF, j1 = w1.x >> 16, j2 = w1.y & 0xFFFF, j3 = w1.y >> 16;
            int k0 = w2.x & 0xFFFF, k1 = w2.x >> 16, k2 = w2.y & 0xFFFF, k3 = w2.y >> 16;
            unsigned p0 = *(const unsigned*)(gfb1 + j0 * 128 + d2);
            unsigned p1 = *(const unsigned*)(gfb1 + j1 * 128 + d2);
            unsigned p2 = *(const unsigned*)(gfb1 + j2 * 128 + d2);
            unsigned p3 = *(const unsigned*)(gfb1 + j3 * 128 + d2);
            unsigned q0 = *(const unsigned*)(gfb2 + k0 * 128 + d2);
            unsigned q1 = *(const unsigned*)(gfb2 + k1 * 128 + d2);
            unsigned q2 = *(const unsigned*)(gfb2 + k2 * 128 + d2);
            unsigned q3 = *(const unsigned*)(gfb2 + k3 * 128 + d2);
            a1A += (blo(p0) + blo(p1)) + (blo(p2) + blo(p3));
            a1B += (bhi(p0) + bhi(p1)) + (bhi(p2) + bhi(p3));
            a2A += (blo(q0) + blo(q1)) + (blo(q2) + blo(q3));
            a2B += (bhi(q0) + bhi(q1)) + (bhi(q2) + bhi(q3));
        }
        for (; e1 + 3 < n1; e1 += 4) {
            uint2 w1 = *(const uint2*)(a1 + e1);
            int j0 = w1.x & 0xFFFF, j1 = w1.x >> 16, j2 = w1.y & 0xFFFF, j3 = w1.y >> 16;
            unsigned p0 = *(const unsigned*)(gfb1 + j0 * 128 + d2);
            unsigned p1 = *(const unsigned*)(gfb1 + j1 * 128 + d2);
            unsigned p2 = *(const unsigned*)(gfb1 + j2 * 128 + d2);
            unsigned p3 = *(const unsigned*)(gfb1 + j3 * 128 + d2);
            a1A += (blo(p0) + blo(p1)) + (blo(p2) + blo(p3));
            a1B += (bhi(p0) + bhi(p1)) + (bhi(p2) + bhi(p3));
        }
        for (; e1 < n1; e1++) {
            unsigned p = *(const unsigned*)(gfb1 + a1[e1] * 128 + d2);
            a1A += blo(p); a1B += bhi(p);
        }
        for (; e2 + 3 < n2; e2 += 4) {
            uint2 w2 = *(const uint2*)(a2 + e2);
            int k0 = w2.x & 0xFFFF, k1 = w2.x >> 16, k2 = w2.y & 0xFFFF, k3 = w2.y >> 16;
            unsigned q0 = *(const unsigned*)(gfb2 + k0 * 128 + d2);
            unsigned q1 = *(const unsigned*)(gfb2 + k1 * 128 + d2);
            unsigned q2 = *(const unsigned*)(gfb2 + k2 * 128 + d2);
            unsigned q3 = *(const unsigned*)(gfb2 + k3 * 128 + d2);
            a2A += (blo(q0) + blo(q1)) + (blo(q2) + blo(q3));
            a2B += (bhi(q0) + bhi(q1)) + (bhi(q2) + bhi(q3));
        }
        for (; e2 < n2; e2++) {
            unsigned q = *(const unsigned*)(gfb2 + a2[e2] * 128 + d2);
            a2A += blo(q); a2B += bhi(q);
        }

        float jc1 = cj_c1[i], jc2 = cj_c2[i];
        float c1n = jc1 * a1A;     // layer-1 cell output, same order as old k_g2c
        float c2n = jc2 * a2A;
        int idx = i * DD + d;
        c1bs[idx] = f2bf(c1n * jc1);
        c2bs[idx] = f2bf(c2n * jc2);
        // u1 = WTH*(cell+c1n); x = u1 + WTH*(cj*accB)  -- same order as unfused pair
        float x1 = WTH * (cell1[idx] + c1n) + WTH * (jc1 * a1B);
        float x2 = WTH * (cell2[idx] + c2n) + WTH * (jc2 * a2B);

        // emb matvec both relations (round-6 readlane construct, verbatim)
        float y1 = bias1, y2 = bias2;
        #pragma unroll
        for (int k = 0; k < DD; k++) {
            float xa = rdlane(x1, k);
            float xb = rdlane(x2, k);
            y1 += xa * Wl[k];
            y2 += xb * Wl[k];
        }
        float t1 = ga * (y1 - me) * inv + be;
        t1 = (t1 > 0.f) ? t1 : expm1f(t1);
        float t2 = ga * (y2 - me) * inv + be;
        t2 = (t2 > 0.f) ? t2 : expm1f(t2);
        uf1b[idx] = f2bf(t1);
        uf2b[idx] = f2bf(t2);
    }
}

// ---------------- decoder: bf16 dot, 8 lanes x 16B per edge ----------------
__global__ __launch_bounds__(256) void k_dec(
    const u16* __restrict__ uf1b, const u16* __restrict__ uf2b,
    const u16* __restrict__ ihb,
    const int* __restrict__ ps1, const int* __restrict__ pd1,
    const int* __restrict__ ps2, const int* __restrict__ pd2,
    float* __restrict__ out)
{
    int t = blockIdx.x * 256 + threadIdx.x;
    int e = t >> 3;
    int l = t & 7;
    if (e >= 2 * NPOS) return;
    const u16* uf; int s, g;
    if (e < NPOS) { uf = uf1b; s = ps1[e];        g = pd1[e];        }
    else          { uf = uf2b; s = ps2[e - NPOS]; g = pd2[e - NPOS]; }
    uint4 av = ((const uint4*)(uf + (size_t)s * DD))[l];
    uint4 cv = ((const uint4*)(ihb + (size_t)g * DD))[l];
    float acc = blo(av.x) * blo(cv.x) + bhi(av.x) * bhi(cv.x)
              + blo(av.y) * blo(cv.y) + bhi(av.y) * bhi(cv.y)
              + blo(av.z) * blo(cv.z) + bhi(av.z) * bhi(cv.z)
              + blo(av.w) * blo(cv.w) + bhi(av.w) * bhi(cv.w);
    acc += __shfl_xor(acc, 4);
    acc += __shfl_xor(acc, 2);
    acc += __shfl_xor(acc, 1);
    if (l == 0) out[e] = acc;
}

extern "C" void kernel_launch(void* const* d_in, const int* in_sizes, int n_in,
                              void* d_out, int out_size, void* d_ws, size_t ws_size,
                              hipStream_t stream)
{
    const float* cell1 = (const float*)d_in[0];
    const float* cell2 = (const float*)d_in[1];
    const float* gfeat = (const float*)d_in[2];
    const float* embW  = (const float*)d_in[3];
    const float* embB  = (const float*)d_in[4];
    const float* bng   = (const float*)d_in[5];
    const float* bnb   = (const float*)d_in[6];
    const float* bnm   = (const float*)d_in[7];
    const float* bnv   = (const float*)d_in[8];
    const int* es1 = (const int*)d_in[9];
    const int* ed1 = (const int*)d_in[10];
    const int* es2 = (const int*)d_in[11];
    const int* ed2 = (const int*)d_in[12];
    const int* ps1 = (const int*)d_in[13];
    const int* pd1 = (const int*)d_in[14];
    const int* ps2 = (const int*)d_in[15];
    const int* pd2 = (const int*)d_in[16];
    float* out = (float*)d_out;

    char* base = (char*)d_ws;
    size_t off = 0;
    auto alloc = [&](size_t bytes) -> void* {
        void* p = base + off;
        off = (off + bytes + 255) & ~(size_t)255;
        return p;
    };
    // zeroed counters first: one small memset covers them
    int* rcnt_c1 = (int*)alloc((size_t)NRNGB * 4);
    int* rcnt_c2 = (int*)alloc((size_t)NRNGB * 4);
    int* rcnt_g1 = (int*)alloc((size_t)NRNGG * 4);
    int* rcnt_g2 = (int*)alloc((size_t)NRNGG * 4);
    size_t cntEnd = off;                       // zero [0, cntEnd)
    int* cnt_c1 = (int*)alloc((size_t)NC * 4); // written dense by k_binfill
    int* cnt_c2 = (int*)alloc((size_t)NC * 4);
    int* cnt_g1 = (int*)alloc((size_t)NG * 4); // written dense by k_binfill_g
    int* cnt_g2 = (int*)alloc((size_t)NG * 4);
    unsigned* rbc1 = (unsigned*)alloc((size_t)NRNGB * RCAP * 4);   // 4.7 MB
    unsigned* rbc2 = (unsigned*)alloc((size_t)NRNGB * RCAP * 4);
    unsigned* rbg1 = (unsigned*)alloc((size_t)NRNGG * RCAPG * 4);  // 4.6 MB
    unsigned* rbg2 = (unsigned*)alloc((size_t)NRNGG * RCAPG * 4);
    u16* adj_c1 = (u16*)alloc((size_t)NC * CSTRIDE * 2);
    u16* adj_c2 = (u16*)alloc((size_t)NC * CSTRIDE * 2);
    u16* adj_g1 = (u16*)alloc((size_t)NG * GSTRIDE * 2);
    u16* adj_g2 = (u16*)alloc((size_t)NG * GSTRIDE * 2);
    float* cj_c1 = (float*)alloc((size_t)NC * 4);
    float* cj_c2 = (float*)alloc((size_t)NC * 4);
    float* ci_g1 = (float*)alloc((size_t)NG * 4);
    float* ci_g2 = (float*)alloc((size_t)NG * 4);
    u16* t1s  = (u16*)alloc((size_t)NC * DD * 2);   // bf16(cell1*cj_c1); reused as uf1b
    u16* t2s  = (u16*)alloc((size_t)NC * DD * 2);   // bf16(cell2*cj_c2); reused as uf2b
    u16* c1bs = (u16*)alloc((size_t)NC * DD * 2);
    u16* c2bs = (u16*)alloc((size_t)NC * DD * 2);
    u16* gfb1 = (u16*)alloc((size_t)NG * DD * 2 * 2);  // interleaved L1|L2 gene table, rel 1 (512 KB)
    u16* gfb2 = (u16*)alloc((size_t)NG * DD * 2 * 2);  // interleaved L1|L2 gene table, rel 2
    float* ih  = (float*)alloc((size_t)NG * DD * 4);
    u16*   ihb = (u16*)alloc((size_t)NG * DD * 2);
    (void)ws_size; (void)in_sizes; (void)n_in; (void)out_size;

    hipMemsetAsync(d_ws, 0, cntEnd, stream);

    dim3 gr((NE + CHUNKB - 1) / CHUNKB, 2);
    k_bin2<<<gr, 256, 0, stream>>>(es1, ed1, es2, ed2,
                                   rcnt_c1, rcnt_c2, rcnt_g1, rcnt_g2,
                                   rbc1, rbc2, rbg1, rbg2);
    dim3 gf(NRNGB, 2);
    k_binfill<<<gf, 256, 0, stream>>>(rcnt_c1, rcnt_c2, rbc1, rbc2,
                                      adj_c1, adj_c2, cnt_c1, cnt_c2,
                                      cell1, cell2, cj_c1, cj_c2, t1s, t2s);
    dim3 gg(NRNGG, 2);
    k_binfill_g<<<gg, 256, 0, stream>>>(rcnt_g1, rcnt_g2, rbg1, rbg2,
                                        adj_g1, adj_g2, cnt_g1, cnt_g2,
                                        gfeat, ci_g1, ci_g2, gfb1, gfb2);

    // ---- layer 1 cell->gene: fills ODD slots of gfb (gn*ci) + ih ----
    k_c2g<<<NG, 256, 0, stream>>>(t1s, t2s, adj_g1, cnt_g1, adj_g2, cnt_g2,
                                  ci_g1, ci_g2, gfb1, gfb2, gfeat, ih, nullptr);
    // ---- FUSED gene->cell layer1+layer2 + emb + BN + ELU (t1s/t2s reused as uf) ----
    k_g2c2_emb<<<2048, 256, 0, stream>>>(gfb1, gfb2,
                                         adj_c1, cnt_c1, adj_c2, cnt_c2,
                                         cj_c1, cj_c2, cell1, cell2,
                                         c1bs, c2bs, t1s, t2s,
                                         embW, embB, bng, bnb, bnm, bnv);
    // ---- layer 2 cell->gene -> ihb ----
    k_c2g<<<NG, 256, 0, stream>>>(c1bs, c2bs, adj_g1, cnt_g1, adj_g2, cnt_g2,
                                  ci_g1, ci_g2, nullptr, nullptr, nullptr, ih, ihb);
    // ---- decoder ----
    k_dec<<<(2 * NPOS * 8 + 255) / 256, 256, 0, stream>>>(t1s, t2s, ihb,
                                                          ps1, pd1, ps2, pd2, out);
}

// Round 13
// 349.629 us; speedup vs baseline: 1.7337x; 1.0161x over previous
//
#include <hip/hip_runtime.h>
#include <math.h>

#define NC   50000
#define NG   2000
#define DD   64
#define NE   1000000
#define NPOS 500000
#define WTH  (1.0f/3.0f)

#define GSTRIDE 640    // gene bucket capacity (mean deg 500, max ~590 observed)
#define CSTRIDE 64     // cell bucket capacity (mean deg 20, max ~45)

#define NRNGB  256     // cell ranges for radix bin
#define RNGCB  196     // cells per range (256*196 = 50176 >= NC)
#define RCAP   4608    // cell-bucket capacity per (range, relation): 3920 +11 sigma
#define NRNGG  250     // gene ranges
#define GPRG   8       // genes per range (250*8 = 2000)
#define RCAPG  4608    // gene-bucket capacity per (range, relation): 4000 +9 sigma
#define CHUNKB 4096    // edges per bin2 block -> 245x2 = 490 blocks

typedef unsigned short u16;
typedef unsigned char  u8;

__device__ __forceinline__ float bf2f(u16 u) {
    return __uint_as_float(((unsigned)u) << 16);
}
__device__ __forceinline__ u16 f2bf(float f) {   // round-to-nearest-even
    unsigned x = __float_as_uint(f);
    return (u16)((x + 0x7FFFu + ((x >> 16) & 1u)) >> 16);
}
__device__ __forceinline__ float blo(unsigned u) { return __uint_as_float(u << 16); }
__device__ __forceinline__ float bhi(unsigned u) { return __uint_as_float(u & 0xFFFF0000u); }
__device__ __forceinline__ float rdlane(float v, int l) {
    return __uint_as_float((unsigned)__builtin_amdgcn_readlane(__float_as_uint(v), l));
}

// ---------------- unified radix bin: edges -> cell buckets AND gene buckets ----------------
// DO NOT replace with direct atomic scatter (round 11: 4M scattered stores -> 215 MB
// write amplification, 300 us). The LDS staging here is what coalesces the writes.
__global__ __launch_bounds__(256) void k_bin2(
    const int* __restrict__ s1, const int* __restrict__ d1,
    const int* __restrict__ s2, const int* __restrict__ d2,
    int* __restrict__ rcnt_c1, int* __restrict__ rcnt_c2,
    int* __restrict__ rcnt_g1, int* __restrict__ rcnt_g2,
    unsigned* __restrict__ rbc1, unsigned* __restrict__ rbc2,
    unsigned* __restrict__ rbg1, unsigned* __restrict__ rbg2)
{
    __shared__ unsigned ed[CHUNKB];            // 16 KB staged edges (src<<16|gene)
    __shared__ unsigned hc[NRNGB], bc[NRNGB];
    __shared__ unsigned hg[NRNGG], bg[NRNGG];
    const int* src; const int* dst; int* rc; int* rg; unsigned* rbc; unsigned* rbg;
    if (blockIdx.y == 0) { src = s1; dst = d1; rc = rcnt_c1; rg = rcnt_g1; rbc = rbc1; rbg = rbg1; }
    else                 { src = s2; dst = d2; rc = rcnt_c2; rg = rcnt_g2; rbc = rbc2; rbg = rbg2; }
    int t = threadIdx.x;
    if (t < NRNGB) hc[t] = 0;
    if (t < NRNGG) hg[t] = 0;
    __syncthreads();
    int e0 = blockIdx.x * CHUNKB;
    #pragma unroll 4
    for (int i = 0; i < CHUNKB / 256; i++) {
        int e = e0 + i * 256 + t;
        unsigned pk = 0xFFFFFFFFu;
        if (e < NE) {
            int s = src[e], g = dst[e];
            pk = ((unsigned)s << 16) | (unsigned)g;
            atomicAdd(&hc[s / RNGCB], 1u);
            atomicAdd(&hg[g >> 3], 1u);
        }
        ed[i * 256 + t] = pk;
    }
    __syncthreads();
    if (t < NRNGB) { unsigned c = hc[t]; bc[t] = c ? (unsigned)atomicAdd(&rc[t], (int)c) : 0u; hc[t] = 0; }
    if (t < NRNGG) { unsigned c = hg[t]; bg[t] = c ? (unsigned)atomicAdd(&rg[t], (int)c) : 0u; hg[t] = 0; }
    __syncthreads();
    #pragma unroll 4
    for (int i = 0; i < CHUNKB / 256; i++) {
        unsigned pk = ed[i * 256 + t];
        if (pk != 0xFFFFFFFFu) {
            int s = (int)(pk >> 16), g = (int)(pk & 0xFFFFu);
            int r1 = s / RNGCB;
            unsigned p = bc[r1] + atomicAdd(&hc[r1], 1u);
            if (p < RCAP)
                rbc[(size_t)r1 * RCAP + p] = ((unsigned)(s - r1 * RNGCB) << 16) | (unsigned)g;
            int r2 = g >> 3;
            unsigned q = bg[r2] + atomicAdd(&hg[r2], 1u);
            if (q < RCAPG)
                rbg[(size_t)r2 * RCAPG + q] = ((unsigned)(g & 7) << 16) | (unsigned)s;
        }
    }
}

// ---------------- cell buckets -> dense adj_c rows + cnt_c + FUSED cell prep ----------------
__global__ __launch_bounds__(256) void k_binfill(
    const int* __restrict__ rcnt1, const int* __restrict__ rcnt2,
    const unsigned* __restrict__ rbuf1, const unsigned* __restrict__ rbuf2,
    u16* __restrict__ adj_c1, u16* __restrict__ adj_c2,
    int* __restrict__ cnt_c1, int* __restrict__ cnt_c2,
    const float* __restrict__ cell1, const float* __restrict__ cell2,
    float* __restrict__ cj_c1, float* __restrict__ cj_c2,
    u16* __restrict__ t1s, u16* __restrict__ t2s)
{
    __shared__ u16 rows[RNGCB * CSTRIDE];       // 24.5 KB
    __shared__ unsigned cur[(RNGCB + 3) / 4];   // packed u8 cursors
    const int* rcnt; const unsigned* rbuf; u16* adj; int* cnt;
    const float* cellF; float* cj; u16* ts;
    if (blockIdx.y == 0) { rcnt = rcnt1; rbuf = rbuf1; adj = adj_c1; cnt = cnt_c1;
                           cellF = cell1; cj = cj_c1; ts = t1s; }
    else                 { rcnt = rcnt2; rbuf = rbuf2; adj = adj_c2; cnt = cnt_c2;
                           cellF = cell2; cj = cj_c2; ts = t2s; }
    int t = threadIdx.x;
    int r = blockIdx.x;
    if (t < (RNGCB + 3) / 4) cur[t] = 0;
    __syncthreads();
    int n = rcnt[r]; if (n > RCAP) n = RCAP;
    const unsigned* buf = rbuf + (size_t)r * RCAP;
    for (int i = t; i < n; i += 256) {
        unsigned e = buf[i];
        unsigned cl = e >> 16;
        unsigned sh = 8u * (cl & 3u);
        unsigned old = atomicAdd(&cur[cl >> 2], 1u << sh);
        unsigned p = (old >> sh) & 0xFFu;
        if (p < CSTRIDE) rows[cl * CSTRIDE + p] = (u16)(e & 0xFFFFu);
    }
    __syncthreads();
    int lo = r * RNGCB;
    int valid = NC - lo; if (valid > RNGCB) valid = RNGCB;
    if (valid <= 0) return;
    if (t < valid) {
        unsigned p = (cur[t >> 2] >> (8u * (t & 3u))) & 0xFFu;
        cnt[lo + t] = (int)((p > CSTRIDE) ? CSTRIDE : p);
    }
    uint4* gd = (uint4*)(adj + (size_t)lo * CSTRIDE);
    const uint4* ls = (const uint4*)rows;
    for (int i = t; i < valid * (CSTRIDE / 8); i += 256) gd[i] = ls[i];
    // fused k_prep cell half for this range/relation
    for (int x = t; x < valid * DD; x += 256) {
        int cl = x >> 6, dd = x & 63;
        unsigned p = (cur[cl >> 2] >> (8u * (cl & 3u))) & 0xFFu;
        int nn = (p > CSTRIDE) ? CSTRIDE : (int)p;
        float j = (nn > 0) ? 1.0f / sqrtf((float)nn) : 0.0f;
        int idx = (lo + cl) * DD + dd;
        ts[idx] = f2bf(cellF[idx] * j);
        if (dd == 0) cj[lo + cl] = j;
    }
}

// ---------------- gene buckets -> dense adj_g rows + cnt_g + FUSED gene prep ----------------
__global__ __launch_bounds__(256) void k_binfill_g(
    const int* __restrict__ rcnt1, const int* __restrict__ rcnt2,
    const unsigned* __restrict__ rbuf1, const unsigned* __restrict__ rbuf2,
    u16* __restrict__ adj_g1, u16* __restrict__ adj_g2,
    int* __restrict__ cnt_g1, int* __restrict__ cnt_g2,
    const float* __restrict__ gfeat,
    float* __restrict__ ci_g1, float* __restrict__ ci_g2,
    u16* __restrict__ gfb1, u16* __restrict__ gfb2)
{
    __shared__ u16 rows[GPRG * GSTRIDE];   // 10 KB staged gene rows
    __shared__ unsigned cur[GPRG];
    const int* rcnt; const unsigned* rbuf; u16* adj; int* cnt; float* ci; u16* gfb;
    if (blockIdx.y == 0) { rcnt = rcnt1; rbuf = rbuf1; adj = adj_g1; cnt = cnt_g1;
                           ci = ci_g1; gfb = gfb1; }
    else                 { rcnt = rcnt2; rbuf = rbuf2; adj = adj_g2; cnt = cnt_g2;
                           ci = ci_g2; gfb = gfb2; }
    int t = threadIdx.x;
    int r = blockIdx.x;
    if (t < GPRG) cur[t] = 0;
    __syncthreads();
    int n = rcnt[r]; if (n > RCAPG) n = RCAPG;
    const unsigned* buf = rbuf + (size_t)r * RCAPG;
    for (int i = t; i < n; i += 256) {
        unsigned e = buf[i];
        unsigned gl = e >> 16;
        unsigned p = atomicAdd(&cur[gl], 1u);
        if (p < GSTRIDE) rows[gl * GSTRIDE + p] = (u16)(e & 0xFFFFu);
    }
    __syncthreads();
    if (t < GPRG) {
        unsigned p = cur[t];
        cnt[r * GPRG + t] = (int)((p > GSTRIDE) ? GSTRIDE : p);
    }
    uint4* gd = (uint4*)(adj + (size_t)r * GPRG * GSTRIDE);
    const uint4* ls = (const uint4*)rows;
    for (int i = t; i < GPRG * GSTRIDE / 8; i += 256) gd[i] = ls[i];
    // fused k_prep gene half for this range/relation (even slots of gfb)
    for (int x = t; x < GPRG * DD; x += 256) {
        int gl = x >> 6, dd = x & 63;
        unsigned p = cur[gl];
        int nn = (p > GSTRIDE) ? GSTRIDE : (int)p;
        float j = (nn > 0) ? 1.0f / sqrtf((float)nn) : 0.0f;
        int gene = r * GPRG + gl;
        int idx = gene * DD + dd;
        gfb[2 * idx] = f2bf(gfeat[idx] * j);
        if (dd == 0) ci[gene] = j;
    }
}

// ---------------- cell->gene SPMM, block per gene, contiguous uint4 index loads ----------------
__global__ __launch_bounds__(256) void k_c2g(
    const u16* __restrict__ src1s, const u16* __restrict__ src2s,
    const u16* __restrict__ adj_g1, const int* __restrict__ cnt_g1,
    const u16* __restrict__ adj_g2, const int* __restrict__ cnt_g2,
    const float* __restrict__ ci_g1, const float* __restrict__ ci_g2,
    u16* __restrict__ gb1s, u16* __restrict__ gb2s,   // nullable: interleaved tables; write ODD slot [2*idx+1]
    const float* __restrict__ gfeat_init,             // non-null: ih = w*(gfeat+gn); else ihb = bf16(ih + w*gn)
    float* __restrict__ ih, u16* __restrict__ ihb)
{
    __shared__ float l1[4][DD];
    __shared__ float l2[4][DD];
    int i   = blockIdx.x;
    int d   = threadIdx.x & 63;
    int grp = threadIdx.x >> 6;

    int n1 = cnt_g1[i]; if (n1 > GSTRIDE) n1 = GSTRIDE;
    const u16* a1 = adj_g1 + i * GSTRIDE;
    float acc1 = 0.f;
    int e = 0;
    for (; e + 32 <= n1; e += 32) {   // group grp owns contiguous 8; one 16B index load
        uint4 w = *(const uint4*)(a1 + e + grp * 8);
        int s0 = w.x & 0xFFFF, s1 = w.x >> 16, s2 = w.y & 0xFFFF, s3 = w.y >> 16;
        int s4 = w.z & 0xFFFF, s5 = w.z >> 16, s6 = w.w & 0xFFFF, s7 = w.w >> 16;
        float v0 = bf2f(src1s[s0 * DD + d]), v1 = bf2f(src1s[s1 * DD + d]);
        float v2 = bf2f(src1s[s2 * DD + d]), v3 = bf2f(src1s[s3 * DD + d]);
        float v4 = bf2f(src1s[s4 * DD + d]), v5 = bf2f(src1s[s5 * DD + d]);
        float v6 = bf2f(src1s[s6 * DD + d]), v7 = bf2f(src1s[s7 * DD + d]);
        acc1 += ((v0 + v1) + (v2 + v3)) + ((v4 + v5) + (v6 + v7));
    }
    for (int q = e + grp; q < n1; q += 4) acc1 += bf2f(src1s[a1[q] * DD + d]);

    int n2 = cnt_g2[i]; if (n2 > GSTRIDE) n2 = GSTRIDE;
    const u16* a2 = adj_g2 + i * GSTRIDE;
    float acc2 = 0.f;
    e = 0;
    for (; e + 32 <= n2; e += 32) {
        uint4 w = *(const uint4*)(a2 + e + grp * 8);
        int s0 = w.x & 0xFFFF, s1 = w.x >> 16, s2 = w.y & 0xFFFF, s3 = w.y >> 16;
        int s4 = w.z & 0xFFFF, s5 = w.z >> 16, s6 = w.w & 0xFFFF, s7 = w.w >> 16;
        float v0 = bf2f(src2s[s0 * DD + d]), v1 = bf2f(src2s[s1 * DD + d]);
        float v2 = bf2f(src2s[s2 * DD + d]), v3 = bf2f(src2s[s3 * DD + d]);
        float v4 = bf2f(src2s[s4 * DD + d]), v5 = bf2f(src2s[s5 * DD + d]);
        float v6 = bf2f(src2s[s6 * DD + d]), v7 = bf2f(src2s[s7 * DD + d]);
        acc2 += ((v0 + v1) + (v2 + v3)) + ((v4 + v5) + (v6 + v7));
    }
    for (int q = e + grp; q < n2; q += 4) acc2 += bf2f(src2s[a2[q] * DD + d]);

    l1[grp][d] = acc1; l2[grp][d] = acc2;
    __syncthreads();
    if (grp == 0) {
        float s1 = l1[0][d] + l1[1][d] + l1[2][d] + l1[3][d];
        float s2 = l2[0][d] + l2[1][d] + l2[2][d] + l2[3][d];
        float ci1 = ci_g1[i], ci2 = ci_g2[i];
        float gn = 0.5f * (ci1 * s1 + ci2 * s2);
        int idx = i * DD + d;
        if (gb1s) { gb1s[2 * idx + 1] = f2bf(gn * ci1); gb2s[2 * idx + 1] = f2bf(gn * ci2); }
        if (gfeat_init) ih[idx] = WTH * (gfeat_init[idx] + gn);
        else            ihb[idx] = f2bf(ih[idx] + WTH * gn);
    }
}

// ---------------- FUSED gene->cell (layer1 + layer2) + emb + BN + ELU ----------------
// Wave per cell (grid-stride); lane d = dim d. ONE pass over adj_c serves both layers:
// per edge, ONE dword gather from the layer-interleaved table per relation
// (lo bf16 = layer-1, hi bf16 = layer-2).
// Main loop widened to 8-EDGE chunks: one uint4 index load per relation (8 u16 idx)
// then 16 independent dword gathers in flight -> 2x memory-level parallelism in the
// latency-bound gather loop (52% VALU / 48% stall at ~3 waves/SIMD, rounds 6-12).
// Matvec: round-6 readlane construct (split-acc neutral r9; Wt preload remats r7).
// DO NOT: (a) float4-LDS matvec (rounds 1-3: ~110 MB scratch spill); (b) launch_bounds
// min-waves > 4 (round 2: VGPR 32 -> 582 MB spill); (c) u32 byte-offset adjacency
// (round 10: net loss). Spill tripwire: WRITE_SIZE > 30 MB.
__global__ __launch_bounds__(256, 4) void k_g2c2_emb(
    const u16* __restrict__ gfb1, const u16* __restrict__ gfb2,  // interleaved [NG][2*DD]
    const u16* __restrict__ adj_c1, const int* __restrict__ cnt_c1,
    const u16* __restrict__ adj_c2, const int* __restrict__ cnt_c2,
    const float* __restrict__ cj_c1, const float* __restrict__ cj_c2,
    const float* __restrict__ cell1, const float* __restrict__ cell2,
    u16* __restrict__ c1bs, u16* __restrict__ c2bs,
    u16* __restrict__ uf1b, u16* __restrict__ uf2b,
    const float* __restrict__ W, const float* __restrict__ bb,
    const float* __restrict__ gam, const float* __restrict__ bet,
    const float* __restrict__ mea, const float* __restrict__ var)
{
    int d = threadIdx.x & 63;
    int wid = blockIdx.x * 4 + (threadIdx.x >> 6);
    int nw = gridDim.x * 4;

    float Wl[DD];
    #pragma unroll
    for (int k = 0; k < DD; k++) Wl[k] = W[k * DD + d];
    float inv = 1.0f / sqrtf(var[d] + 1e-5f);
    float ga = gam[d], be = bet[d], me = mea[d];
    float bias1 = bb[d] + W[DD * DD + d];
    float bias2 = bb[d] + W[(DD + 1) * DD + d];
    int d2 = 2 * d;

    for (int i = wid; i < NC; i += nw) {
        int n1 = cnt_c1[i]; if (n1 > CSTRIDE) n1 = CSTRIDE;
        int n2 = cnt_c2[i]; if (n2 > CSTRIDE) n2 = CSTRIDE;
        const u16* a1 = adj_c1 + (size_t)i * CSTRIDE;
        const u16* a2 = adj_c2 + (size_t)i * CSTRIDE;
        float a1A = 0.f, a2A = 0.f;   // layer-1 sums (rel 1, rel 2)
        float a1B = 0.f, a2B = 0.f;   // layer-2 sums
        int e1 = 0, e2 = 0;
        // ---- 8-edge lockstep main loop: 2 uint4 idx loads + 16 gathers in flight ----
        int m1 = n1 & ~7, m2 = n2 & ~7;
        int m8 = (m1 < m2) ? m1 : m2;
        for (; e1 < m8; e1 += 8, e2 += 8) {
            uint4 w1 = *(const uint4*)(a1 + e1);
            uint4 w2 = *(const uint4*)(a2 + e2);
            int j0 = w1.x & 0xFFFF, j1 = w1.x >> 16, j2 = w1.y & 0xFFFF, j3 = w1.y >> 16;
            int j4 = w1.z & 0xFFFF, j5 = w1.z >> 16, j6 = w1.w & 0xFFFF, j7 = w1.w >> 16;
            int k0 = w2.x & 0xFFFF, k1 = w2.x >> 16, k2 = w2.y & 0xFFFF, k3 = w2.y >> 16;
            int k4 = w2.z & 0xFFFF, k5 = w2.z >> 16, k6 = w2.w & 0xFFFF, k7 = w2.w >> 16;
            unsigned p0 = *(const unsigned*)(gfb1 + j0 * 128 + d2);
            unsigned p1 = *(const unsigned*)(gfb1 + j1 * 128 + d2);
            unsigned p2 = *(const unsigned*)(gfb1 + j2 * 128 + d2);
            unsigned p3 = *(const unsigned*)(gfb1 + j3 * 128 + d2);
            unsigned p4 = *(const unsigned*)(gfb1 + j4 * 128 + d2);
            unsigned p5 = *(const unsigned*)(gfb1 + j5 * 128 + d2);
            unsigned p6 = *(const unsigned*)(gfb1 + j6 * 128 + d2);
            unsigned p7 = *(const unsigned*)(gfb1 + j7 * 128 + d2);
            unsigned q0 = *(const unsigned*)(gfb2 + k0 * 128 + d2);
            unsigned q1 = *(const unsigned*)(gfb2 + k1 * 128 + d2);
            unsigned q2 = *(const unsigned*)(gfb2 + k2 * 128 + d2);
            unsigned q3 = *(const unsigned*)(gfb2 + k3 * 128 + d2);
            unsigned q4 = *(const unsigned*)(gfb2 + k4 * 128 + d2);
            unsigned q5 = *(const unsigned*)(gfb2 + k5 * 128 + d2);
            unsigned q6 = *(const unsigned*)(gfb2 + k6 * 128 + d2);
            unsigned q7 = *(const unsigned*)(gfb2 + k7 * 128 + d2);
            a1A += ((blo(p0) + blo(p1)) + (blo(p2) + blo(p3)))
                 + ((blo(p4) + blo(p5)) + (blo(p6) + blo(p7)));
            a1B += ((bhi(p0) + bhi(p1)) + (bhi(p2) + bhi(p3)))
                 + ((bhi(p4) + bhi(p5)) + (bhi(p6) + bhi(p7)));
            a2A += ((blo(q0) + blo(q1)) + (blo(q2) + blo(q3)))
                 + ((blo(q4) + blo(q5)) + (blo(q6) + blo(q7)));
            a2B += ((bhi(q0) + bhi(q1)) + (bhi(q2) + bhi(q3)))
                 + ((bhi(q4) + bhi(q5)) + (bhi(q6) + bhi(q7)));
        }
        // ---- 4-wide tails per relation ----
        for (; e1 + 3 < n1; e1 += 4) {
            uint2 w1 = *(const uint2*)(a1 + e1);
            int j0 = w1.x & 0xFFFF, j1 = w1.x >> 16, j2 = w1.y & 0xFFFF, j3 = w1.y >> 16;
            unsigned p0 = *(const unsigned*)(gfb1 + j0 * 128 + d2);
            unsigned p1 = *(const unsigned*)(gfb1 + j1 * 128 + d2);
            unsigned p2 = *(const unsigned*)(gfb1 + j2 * 128 + d2);
            unsigned p3 = *(const unsigned*)(gfb1 + j3 * 128 + d2);
            a1A += (blo(p0) + blo(p1)) + (blo(p2) + blo(p3));
            a1B += (bhi(p0) + bhi(p1)) + (bhi(p2) + bhi(p3));
        }
        for (; e1 < n1; e1++) {
            unsigned p = *(const unsigned*)(gfb1 + a1[e1] * 128 + d2);
            a1A += blo(p); a1B += bhi(p);
        }
        for (; e2 + 3 < n2; e2 += 4) {
            uint2 w2 = *(const uint2*)(a2 + e2);
            int k0 = w2.x & 0xFFFF, k1 = w2.x >> 16, k2 = w2.y & 0xFFFF, k3 = w2.y >> 16;
            unsigned q0 = *(const unsigned*)(gfb2 + k0 * 128 + d2);
            unsigned q1 = *(const unsigned*)(gfb2 + k1 * 128 + d2);
            unsigned q2 = *(const unsigned*)(gfb2 + k2 * 128 + d2);
            unsigned q3 = *(const unsigned*)(gfb2 + k3 * 128 + d2);
            a2A += (blo(q0) + blo(q1)) + (blo(q2) + blo(q3));
            a2B += (bhi(q0) + bhi(q1)) + (bhi(q2) + bhi(q3));
        }
        for (; e2 < n2; e2++) {
            unsigned q = *(const unsigned*)(gfb2 + a2[e2] * 128 + d2);
            a2A += blo(q); a2B += bhi(q);
        }

        float jc1 = cj_c1[i], jc2 = cj_c2[i];
        float c1n = jc1 * a1A;     // layer-1 cell output
        float c2n = jc2 * a2A;
        int idx = i * DD + d;
        c1bs[idx] = f2bf(c1n * jc1);
        c2bs[idx] = f2bf(c2n * jc2);
        // u1 = WTH*(cell+c1n); x = u1 + WTH*(cj*accB)  -- same order as unfused pair
        float x1 = WTH * (cell1[idx] + c1n) + WTH * (jc1 * a1B);
        float x2 = WTH * (cell2[idx] + c2n) + WTH * (jc2 * a2B);

        // emb matvec both relations (round-6 readlane construct, verbatim)
        float y1 = bias1, y2 = bias2;
        #pragma unroll
        for (int k = 0; k < DD; k++) {
            float xa = rdlane(x1, k);
            float xb = rdlane(x2, k);
            y1 += xa * Wl[k];
            y2 += xb * Wl[k];
        }
        float t1 = ga * (y1 - me) * inv + be;
        t1 = (t1 > 0.f) ? t1 : expm1f(t1);
        float t2 = ga * (y2 - me) * inv + be;
        t2 = (t2 > 0.f) ? t2 : expm1f(t2);
        uf1b[idx] = f2bf(t1);
        uf2b[idx] = f2bf(t2);
    }
}

// ---------------- decoder: bf16 dot, 8 lanes x 16B per edge ----------------
__global__ __launch_bounds__(256) void k_dec(
    const u16* __restrict__ uf1b, const u16* __restrict__ uf2b,
    const u16* __restrict__ ihb,
    const int* __restrict__ ps1, const int* __restrict__ pd1,
    const int* __restrict__ ps2, const int* __restrict__ pd2,
    float* __restrict__ out)
{
    int t = blockIdx.x * 256 + threadIdx.x;
    int e = t >> 3;
    int l = t & 7;
    if (e >= 2 * NPOS) return;
    const u16* uf; int s, g;
    if (e < NPOS) { uf = uf1b; s = ps1[e];        g = pd1[e];        }
    else          { uf = uf2b; s = ps2[e - NPOS]; g = pd2[e - NPOS]; }
    uint4 av = ((const uint4*)(uf + (size_t)s * DD))[l];
    uint4 cv = ((const uint4*)(ihb + (size_t)g * DD))[l];
    float acc = blo(av.x) * blo(cv.x) + bhi(av.x) * bhi(cv.x)
              + blo(av.y) * blo(cv.y) + bhi(av.y) * bhi(cv.y)
              + blo(av.z) * blo(cv.z) + bhi(av.z) * bhi(cv.z)
              + blo(av.w) * blo(cv.w) + bhi(av.w) * bhi(cv.w);
    acc += __shfl_xor(acc, 4);
    acc += __shfl_xor(acc, 2);
    acc += __shfl_xor(acc, 1);
    if (l == 0) out[e] = acc;
}

extern "C" void kernel_launch(void* const* d_in, const int* in_sizes, int n_in,
                              void* d_out, int out_size, void* d_ws, size_t ws_size,
                              hipStream_t stream)
{
    const float* cell1 = (const float*)d_in[0];
    const float* cell2 = (const float*)d_in[1];
    const float* gfeat = (const float*)d_in[2];
    const float* embW  = (const float*)d_in[3];
    const float* embB  = (const float*)d_in[4];
    const float* bng   = (const float*)d_in[5];
    const float* bnb   = (const float*)d_in[6];
    const float* bnm   = (const float*)d_in[7];
    const float* bnv   = (const float*)d_in[8];
    const int* es1 = (const int*)d_in[9];
    const int* ed1 = (const int*)d_in[10];
    const int* es2 = (const int*)d_in[11];
    const int* ed2 = (const int*)d_in[12];
    const int* ps1 = (const int*)d_in[13];
    const int* pd1 = (const int*)d_in[14];
    const int* ps2 = (const int*)d_in[15];
    const int* pd2 = (const int*)d_in[16];
    float* out = (float*)d_out;

    char* base = (char*)d_ws;
    size_t off = 0;
    auto alloc = [&](size_t bytes) -> void* {
        void* p = base + off;
        off = (off + bytes + 255) & ~(size_t)255;
        return p;
    };
    // zeroed counters first: one small memset covers them
    int* rcnt_c1 = (int*)alloc((size_t)NRNGB * 4);
    int* rcnt_c2 = (int*)alloc((size_t)NRNGB * 4);
    int* rcnt_g1 = (int*)alloc((size_t)NRNGG * 4);
    int* rcnt_g2 = (int*)alloc((size_t)NRNGG * 4);
    size_t cntEnd = off;                       // zero [0, cntEnd)
    int* cnt_c1 = (int*)alloc((size_t)NC * 4); // written dense by k_binfill
    int* cnt_c2 = (int*)alloc((size_t)NC * 4);
    int* cnt_g1 = (int*)alloc((size_t)NG * 4); // written dense by k_binfill_g
    int* cnt_g2 = (int*)alloc((size_t)NG * 4);
    unsigned* rbc1 = (unsigned*)alloc((size_t)NRNGB * RCAP * 4);   // 4.7 MB
    unsigned* rbc2 = (unsigned*)alloc((size_t)NRNGB * RCAP * 4);
    unsigned* rbg1 = (unsigned*)alloc((size_t)NRNGG * RCAPG * 4);  // 4.6 MB
    unsigned* rbg2 = (unsigned*)alloc((size_t)NRNGG * RCAPG * 4);
    u16* adj_c1 = (u16*)alloc((size_t)NC * CSTRIDE * 2);
    u16* adj_c2 = (u16*)alloc((size_t)NC * CSTRIDE * 2);
    u16* adj_g1 = (u16*)alloc((size_t)NG * GSTRIDE * 2);
    u16* adj_g2 = (u16*)alloc((size_t)NG * GSTRIDE * 2);
    float* cj_c1 = (float*)alloc((size_t)NC * 4);
    float* cj_c2 = (float*)alloc((size_t)NC * 4);
    float* ci_g1 = (float*)alloc((size_t)NG * 4);
    float* ci_g2 = (float*)alloc((size_t)NG * 4);
    u16* t1s  = (u16*)alloc((size_t)NC * DD * 2);   // bf16(cell1*cj_c1); reused as uf1b
    u16* t2s  = (u16*)alloc((size_t)NC * DD * 2);   // bf16(cell2*cj_c2); reused as uf2b
    u16* c1bs = (u16*)alloc((size_t)NC * DD * 2);
    u16* c2bs = (u16*)alloc((size_t)NC * DD * 2);
    u16* gfb1 = (u16*)alloc((size_t)NG * DD * 2 * 2);  // interleaved L1|L2 gene table, rel 1 (512 KB)
    u16* gfb2 = (u16*)alloc((size_t)NG * DD * 2 * 2);  // interleaved L1|L2 gene table, rel 2
    float* ih  = (float*)alloc((size_t)NG * DD * 4);
    u16*   ihb = (u16*)alloc((size_t)NG * DD * 2);
    (void)ws_size; (void)in_sizes; (void)n_in; (void)out_size;

    hipMemsetAsync(d_ws, 0, cntEnd, stream);

    dim3 gr((NE + CHUNKB - 1) / CHUNKB, 2);
    k_bin2<<<gr, 256, 0, stream>>>(es1, ed1, es2, ed2,
                                   rcnt_c1, rcnt_c2, rcnt_g1, rcnt_g2,
                                   rbc1, rbc2, rbg1, rbg2);
    dim3 gf(NRNGB, 2);
    k_binfill<<<gf, 256, 0, stream>>>(rcnt_c1, rcnt_c2, rbc1, rbc2,
                                      adj_c1, adj_c2, cnt_c1, cnt_c2,
                                      cell1, cell2, cj_c1, cj_c2, t1s, t2s);
    dim3 gg(NRNGG, 2);
    k_binfill_g<<<gg, 256, 0, stream>>>(rcnt_g1, rcnt_g2, rbg1, rbg2,
                                        adj_g1, adj_g2, cnt_g1, cnt_g2,
                                        gfeat, ci_g1, ci_g2, gfb1, gfb2);

    // ---- layer 1 cell->gene: fills ODD slots of gfb (gn*ci) + ih ----
    k_c2g<<<NG, 256, 0, stream>>>(t1s, t2s, adj_g1, cnt_g1, adj_g2, cnt_g2,
                                  ci_g1, ci_g2, gfb1, gfb2, gfeat, ih, nullptr);
    // ---- FUSED gene->cell layer1+layer2 + emb + BN + ELU (t1s/t2s reused as uf) ----
    k_g2c2_emb<<<2048, 256, 0, stream>>>(gfb1, gfb2,
                                         adj_c1, cnt_c1, adj_c2, cnt_c2,
                                         cj_c1, cj_c2, cell1, cell2,
                                         c1bs, c2bs, t1s, t2s,
                                         embW, embB, bng, bnb, bnm, bnv);
    // ---- layer 2 cell->gene -> ihb ----
    k_c2g<<<NG, 256, 0, stream>>>(c1bs, c2bs, adj_g1, cnt_g1, adj_g2, cnt_g2,
                                  ci_g1, ci_g2, nullptr, nullptr, nullptr, ih, ihb);
    // ---- decoder ----
    k_dec<<<(2 * NPOS * 8 + 255) / 256, 256, 0, stream>>>(t1s, t2s, ihb,
                                                          ps1, pd1, ps2, pd2, out);
}